// Round 1
// baseline (199.337 us; speedup 1.0000x reference)
//
#include <hip/hip_runtime.h>

#define NQ   7
#define DIM  128   // 2^7

// One wave (64 threads) per block; each thread owns one full row (128 floats in
// registers). Wave cooperatively stages 64 rows through LDS in 4 column-chunks
// so global loads are coalesced float4 while each thread still gets its whole
// row. LDS row stride = 33 dwords -> bank = (lane + 4j) % 32 on reads: 2-way
// aliasing only (free).
__global__ __launch_bounds__(64, 2)
void qnat_kernel(const float* __restrict__ embed,
                 const float* __restrict__ theta,
                 float* __restrict__ out)
{
    __shared__ float lds[64 * 33];          // 8448 B
    const int lane = threadIdx.x;           // 0..63
    const size_t rowBase = (size_t)blockIdx.x * 64;
    const float4* __restrict__ g4 =
        reinterpret_cast<const float4*>(embed + rowBase * DIM);
    const int gr = lane >> 3;               // row sub-index within a load instr
    const int gq = lane & 7;                // float4 index within a row-chunk

    float st[DIM];

    // ---- stage 64 rows x 128 floats via LDS, 4 chunks of 32 columns ----
    float4 buf[8];
#pragma unroll
    for (int j = 0; j < 8; ++j)
        buf[j] = g4[(j * 8 + gr) * 32 + gq];                 // chunk 0

#pragma unroll
    for (int c = 0; c < 4; ++c) {
        float4 nxt[8];
        if (c < 3) {
#pragma unroll
            for (int j = 0; j < 8; ++j)
                nxt[j] = g4[(j * 8 + gr) * 32 + (c + 1) * 8 + gq];  // prefetch
        }
#pragma unroll
        for (int j = 0; j < 8; ++j) {
            const int base = (j * 8 + gr) * 33 + gq * 4;
            lds[base + 0] = buf[j].x;
            lds[base + 1] = buf[j].y;
            lds[base + 2] = buf[j].z;
            lds[base + 3] = buf[j].w;
        }
        __syncthreads();
#pragma unroll
        for (int j = 0; j < 8; ++j) {
            const int base = lane * 33 + j * 4;
            st[c * 32 + j * 4 + 0] = lds[base + 0];
            st[c * 32 + j * 4 + 1] = lds[base + 1];
            st[c * 32 + j * 4 + 2] = lds[base + 2];
            st[c * 32 + j * 4 + 3] = lds[base + 3];
        }
        __syncthreads();
        if (c < 3) {
#pragma unroll
            for (int j = 0; j < 8; ++j) buf[j] = nxt[j];
        }
    }

    // ---- normalize ----
    float ss = 0.f;
#pragma unroll
    for (int i = 0; i < DIM; ++i) ss = fmaf(st[i], st[i], ss);
    const float inv = __builtin_amdgcn_rsqf(ss);
#pragma unroll
    for (int i = 0; i < DIM; ++i) st[i] *= inv;

    // ---- 2 layers of (7 RY gates + CZ ladder phase) ----
#pragma clang loop unroll(disable)
    for (int d = 0; d < 2; ++d) {
#pragma unroll
        for (int q = 0; q < NQ; ++q) {
            const float half = 0.5f * theta[d * NQ + q];
            const float c_ = __cosf(half);
            const float s_ = __sinf(half);
            const int lo = 1 << q;
#pragma unroll
            for (int p = 0; p < 64; ++p) {
                const int i0 = ((p >> q) << (q + 1)) | (p & (lo - 1));
                const int i1 = i0 | lo;
                const float a0 = st[i0], a1 = st[i1];
                st[i0] = fmaf(c_, a0, -s_ * a1);
                st[i1] = fmaf(s_, a0,  c_ * a1);
            }
        }
        // CZ phase: (-1)^(sum of adjacent bit products) — compile-time signs
#pragma unroll
        for (int i = 0; i < DIM; ++i) {
            int par = 0;
#pragma unroll
            for (int j = 0; j < NQ - 1; ++j)
                par ^= ((i >> j) & 1) & ((i >> (j + 1)) & 1);
            if (par) st[i] = -st[i];
        }
    }

    // ---- probs ----
#pragma unroll
    for (int i = 0; i < DIM; ++i) st[i] *= st[i];

    // ---- out[k] = sum_i probs[i]*(1-2*bit_k(i)) : halving sum/diff tree ----
    float o[NQ];
#pragma unroll
    for (int k = 0; k < NQ; ++k) {
        const int n = DIM >> (k + 1);
        float acc = 0.f;
#pragma unroll
        for (int i = 0; i < 64; ++i) {
            if (i < n) {
                const float a = st[2 * i], b = st[2 * i + 1];
                acc += a - b;
                st[i] = a + b;     // safe in-place: write idx i <= read idx 2i
            }
        }
        o[k] = acc;
    }

    // ---- repack through LDS for coalesced stores ----
    __syncthreads();
#pragma unroll
    for (int k = 0; k < NQ; ++k) lds[lane * NQ + k] = o[k];
    __syncthreads();
    float* __restrict__ ob = out + rowBase * NQ;
#pragma unroll
    for (int k = 0; k < NQ; ++k) ob[k * 64 + lane] = lds[k * 64 + lane];
}

extern "C" void kernel_launch(void* const* d_in, const int* in_sizes, int n_in,
                              void* d_out, int out_size, void* d_ws, size_t ws_size,
                              hipStream_t stream)
{
    const float* embed = (const float*)d_in[0];
    const float* theta = (const float*)d_in[1];
    float* out = (float*)d_out;
    const int batch = in_sizes[0] / DIM;          // 262144
    dim3 grid(batch / 64), block(64);
    hipLaunchKernelGGL(qnat_kernel, grid, block, 0, stream, embed, theta, out);
}